// Round 13
// baseline (144.447 us; speedup 1.0000x reference)
//
#include <hip/hip_runtime.h>
#include <math.h>

#define NTHREADS 256

// 16 node weight pointers.
struct PW {
    const float* w[16];
    int perp[16];
};

// ---------------------------------------------------------------------------
// LDS arena per sample (floats). Structure identical to R9/R11 (verified).
// ---------------------------------------------------------------------------
constexpr int SA = 0, SB = 1296, SC = 2592, SP = 3888;
constexpr int W0A = 4104, W2A = 4140, W20A = 4356, W31A = 4572, W3A = 4788;
constexpr int ARENA = 5004;   // 2*5004*4 = 40032 B -> 4 blocks/CU

// Staging with permutation.
template<int D0, int D1, int D2, int D3, int S0, int S1, int S2, int S3, int DST>
__device__ __forceinline__ void stg_pm(float* __restrict__ lds, const float* __restrict__ W,
                                       float a0, float b0, float a1, float b1, int tid) {
    constexpr int TOT = D0 * D1 * D2 * D3;
    for (int e = tid; e < 2 * TOT; e += NTHREADS) {
        const int s = (e >= TOT);
        const int d = e - s * TOT;
        int r = d;
        const int i3 = r % D3; r /= D3;
        const int i2 = r % D2; r /= D2;
        const int i1 = r % D1;
        const int i0 = r / D1;
        const int src = i0 * S0 + i1 * S1 + i2 * S2 + i3 * S3;
        const float al = s ? a1 : a0, be = s ? b1 : b0;
        lds[s * ARENA + DST + d] = al * W[src] + be * W[TOT + src];
    }
}

// ---------------------------------------------------------------------------
// Fused gram: one wave computes {<w0,w0>,<w0,w1>,<w1,w1>} partials for a node
// segment [start,start+count) and stores to gpart[(node*4+wv)*3+{0,1,2}].
// Weights are L2/L3-hot (shared by all 1024 blocks) -> cheap per block.
// ---------------------------------------------------------------------------
__device__ __forceinline__ void gram_node(const PW& pw, int node, int start, int count,
                                          int lane, int wv, float* __restrict__ gpart) {
    const float* __restrict__ W = pw.w[node];
    const int m = pw.perp[node];
    float s00 = 0.f, s01 = 0.f, s11 = 0.f;
    for (int q = start / 4 + lane; q < (start + count) / 4; q += 64) {
        const float4 a = *reinterpret_cast<const float4*>(W + 4 * q);
        const float4 b = *reinterpret_cast<const float4*>(W + m + 4 * q);
        s00 += a.x * a.x + a.y * a.y + a.z * a.z + a.w * a.w;
        s01 += a.x * b.x + a.y * b.y + a.z * b.z + a.w * b.w;
        s11 += b.x * b.x + b.y * b.y + b.z * b.z + b.w * b.w;
    }
    for (int off = 32; off > 0; off >>= 1) {
        s00 += __shfl_down(s00, off, 64);
        s01 += __shfl_down(s01, off, 64);
        s11 += __shfl_down(s11, off, 64);
    }
    if (lane == 0) {
        gpart[(node * 4 + wv) * 3 + 0] = s00;
        gpart[(node * 4 + wv) * 3 + 1] = s01;
        gpart[(node * 4 + wv) * 3 + 2] = s11;
    }
}

// ---------------------------------------------------------------------------
// mm cores with PACKED accumulators (R11-verified).
// ---------------------------------------------------------------------------
#define PK_FMA(ACC, AV, BV) { (ACC).x += (AV) * (BV).x; (ACC).y += (AV) * (BV).y; }

template<int M, int N, int K, int TM, int TN, int AOFF, int BOFF>
__device__ __forceinline__ void mm_acc(const float* __restrict__ lds, int tid,
                                       float2 (&acc)[TM][TN / 2]) {
    constexpr int WM = M / TM, WN = N / TN, PER_S = WM * WN, TOT = 2 * PER_S;
    static_assert(TOT <= NTHREADS, "tile overflow");
    if (tid >= TOT) return;
    const int s = (tid >= PER_S);
    const int r = tid - s * PER_S;
    const int mt = r / WN, nt = r - mt * WN;
    const float* __restrict__ Ab = lds + s * ARENA + AOFF + mt * TM;
    const float* __restrict__ Bb = lds + s * ARENA + BOFF + nt * TN;
#pragma unroll
    for (int i = 0; i < TM; i++)
#pragma unroll
        for (int j = 0; j < TN / 2; j++) { acc[i][j].x = 0.f; acc[i][j].y = 0.f; }
#pragma unroll 6
    for (int k = 0; k < K; ++k) {
        float a[TM]; float2 b[TN / 2];
        if constexpr (TM == 4) {
            const float4 v = *reinterpret_cast<const float4*>(Ab + k * M);
            a[0] = v.x; a[1] = v.y; a[2] = v.z; a[3] = v.w;
        } else {
            const float2 v = *reinterpret_cast<const float2*>(Ab + k * M);
            a[0] = v.x; a[1] = v.y;
        }
        if constexpr (TN == 4) {
            const float4 v = *reinterpret_cast<const float4*>(Bb + k * N);
            b[0].x = v.x; b[0].y = v.y; b[1].x = v.z; b[1].y = v.w;
        } else {
            b[0] = *reinterpret_cast<const float2*>(Bb + k * N);
        }
#pragma unroll
        for (int i = 0; i < TM; i++)
#pragma unroll
            for (int j = 0; j < TN / 2; j++) PK_FMA(acc[i][j], a[i], b[j]);
    }
}

// A from LDS, B from GLOBAL identity weight (planes W, W+PL), packed combine.
template<int M, int N, int K, int TM, int TN, int AOFF, int PL>
__device__ __forceinline__ void mm_accGB(const float* __restrict__ lds,
                                         const float* __restrict__ W,
                                         float a0, float b0, float a1, float b1,
                                         int tid, float2 (&acc)[TM][TN / 2]) {
    constexpr int WM = M / TM, WN = N / TN, PER_S = WM * WN, TOT = 2 * PER_S;
    static_assert(TOT <= NTHREADS, "tile overflow");
    if (tid >= TOT) return;
    const int s = (tid >= PER_S);
    const int r = tid - s * PER_S;
    const int mt = r / WN, nt = r - mt * WN;
    const float al = s ? a1 : a0, be = s ? b1 : b0;
    const float* __restrict__ Ab = lds + s * ARENA + AOFF + mt * TM;
    const float* __restrict__ Bb = W + nt * TN;
#pragma unroll
    for (int i = 0; i < TM; i++)
#pragma unroll
        for (int j = 0; j < TN / 2; j++) { acc[i][j].x = 0.f; acc[i][j].y = 0.f; }
#pragma unroll 6
    for (int k = 0; k < K; ++k) {
        float a[TM]; float2 b[TN / 2];
        if constexpr (TM == 4) {
            const float4 v = *reinterpret_cast<const float4*>(Ab + k * M);
            a[0] = v.x; a[1] = v.y; a[2] = v.z; a[3] = v.w;
        } else {
            const float2 v = *reinterpret_cast<const float2*>(Ab + k * M);
            a[0] = v.x; a[1] = v.y;
        }
        if constexpr (TN == 4) {
            const float4 u0 = *reinterpret_cast<const float4*>(Bb + k * N);
            const float4 u1 = *reinterpret_cast<const float4*>(Bb + PL + k * N);
            b[0].x = al * u0.x + be * u1.x; b[0].y = al * u0.y + be * u1.y;
            b[1].x = al * u0.z + be * u1.z; b[1].y = al * u0.w + be * u1.w;
        } else {
            const float2 u0 = *reinterpret_cast<const float2*>(Bb + k * N);
            const float2 u1 = *reinterpret_cast<const float2*>(Bb + PL + k * N);
            b[0].x = al * u0.x + be * u1.x; b[0].y = al * u0.y + be * u1.y;
        }
#pragma unroll
        for (int i = 0; i < TM; i++)
#pragma unroll
            for (int j = 0; j < TN / 2; j++) PK_FMA(acc[i][j], a[i], b[j]);
    }
}

// A from GLOBAL identity weight, B from LDS.
template<int M, int N, int K, int TM, int TN, int BOFF, int PL>
__device__ __forceinline__ void mm_accGA(const float* __restrict__ lds,
                                         const float* __restrict__ W,
                                         float a0, float b0, float a1, float b1,
                                         int tid, float2 (&acc)[TM][TN / 2]) {
    constexpr int WM = M / TM, WN = N / TN, PER_S = WM * WN, TOT = 2 * PER_S;
    static_assert(TOT <= NTHREADS, "tile overflow");
    if (tid >= TOT) return;
    const int s = (tid >= PER_S);
    const int r = tid - s * PER_S;
    const int mt = r / WN, nt = r - mt * WN;
    const float al = s ? a1 : a0, be = s ? b1 : b0;
    const float* __restrict__ Ab = W + mt * TM;
    const float* __restrict__ Bb = lds + s * ARENA + BOFF + nt * TN;
#pragma unroll
    for (int i = 0; i < TM; i++)
#pragma unroll
        for (int j = 0; j < TN / 2; j++) { acc[i][j].x = 0.f; acc[i][j].y = 0.f; }
#pragma unroll 6
    for (int k = 0; k < K; ++k) {
        float a[TM]; float2 b[TN / 2];
        if constexpr (TM == 4) {
            const float4 u0 = *reinterpret_cast<const float4*>(Ab + k * M);
            const float4 u1 = *reinterpret_cast<const float4*>(Ab + PL + k * M);
            a[0] = al * u0.x + be * u1.x; a[1] = al * u0.y + be * u1.y;
            a[2] = al * u0.z + be * u1.z; a[3] = al * u0.w + be * u1.w;
        } else {
            const float2 u0 = *reinterpret_cast<const float2*>(Ab + k * M);
            const float2 u1 = *reinterpret_cast<const float2*>(Ab + PL + k * M);
            a[0] = al * u0.x + be * u1.x; a[1] = al * u0.y + be * u1.y;
        }
        if constexpr (TN == 4) {
            const float4 v = *reinterpret_cast<const float4*>(Bb + k * N);
            b[0].x = v.x; b[0].y = v.y; b[1].x = v.z; b[1].y = v.w;
        } else {
            b[0] = *reinterpret_cast<const float2*>(Bb + k * N);
        }
#pragma unroll
        for (int i = 0; i < TM; i++)
#pragma unroll
            for (int j = 0; j < TN / 2; j++) PK_FMA(acc[i][j], a[i], b[j]);
    }
}

// Scalar accessor into packed acc (compile-time j in unrolled loops).
template<int TM, int TNH>
__device__ __forceinline__ float accv(const float2 (&acc)[TM][TNH], int i, int j) {
    return (j & 1) ? acc[i][j >> 1].y : acc[i][j >> 1].x;
}

// Write with per-axis strides (stride lists verified R2/R7/R9/R11).
template<int M, int N, int TM, int TN,
         int NM2, int OSM1, int OSM2, int NN2, int OSN1, int OSN2, int OOFF>
__device__ __forceinline__ void mm_wr(float* __restrict__ lds, int tid,
                                      const float2 (&acc)[TM][TN / 2]) {
    constexpr int WM = M / TM, WN = N / TN, PER_S = WM * WN, TOT = 2 * PER_S;
    if (tid >= TOT) return;
    const int s = (tid >= PER_S);
    const int r = tid - s * PER_S;
    const int mt = r / WN, nt = r - mt * WN;
    float* __restrict__ Ob = lds + s * ARENA + OOFF;
    constexpr bool NCONT = (TN == 4) && (OSN2 == 1) && ((NN2 >= N) || (OSN1 == NN2));
    constexpr bool MCONT = (TM == 4) && (OSM2 == 1) && ((NM2 >= M) || (OSM1 == NM2));
    if constexpr (NCONT) {
        const int nb = nt * TN;
#pragma unroll
        for (int i = 0; i < TM; i++) {
            const int m = mt * TM + i;
            int m1, m2;
            if constexpr (NM2 >= M) { m1 = 0; m2 = m; }
            else                    { m1 = m / NM2; m2 = m - m1 * NM2; }
            float4 v; v.x = acc[i][0].x; v.y = acc[i][0].y; v.z = acc[i][1].x; v.w = acc[i][1].y;
            *reinterpret_cast<float4*>(Ob + m1 * OSM1 + m2 * OSM2 + nb) = v;
        }
    } else if constexpr (MCONT) {
        const int mb = mt * TM;
#pragma unroll
        for (int j = 0; j < TN; j++) {
            const int n = nt * TN + j;
            int n1, n2;
            if constexpr (NN2 >= N) { n1 = 0; n2 = n; }
            else                    { n1 = n / NN2; n2 = n - n1 * NN2; }
            float4 v;
            v.x = accv(acc, 0, j); v.y = accv(acc, 1, j);
            v.z = accv(acc, 2, j); v.w = accv(acc, 3, j);
            *reinterpret_cast<float4*>(Ob + n1 * OSN1 + n2 * OSN2 + mb) = v;
        }
    } else {
#pragma unroll
        for (int i = 0; i < TM; i++) {
            const int m = mt * TM + i;
            int m1, m2;
            if constexpr (NM2 >= M) { m1 = 0; m2 = m; }
            else                    { m1 = m / NM2; m2 = m - m1 * NM2; }
#pragma unroll
            for (int j = 0; j < TN; j++) {
                const int n = nt * TN + j;
                int n1, n2;
                if constexpr (NN2 >= N) { n1 = 0; n2 = n; }
                else                    { n1 = n / NN2; n2 = n - n1 * NN2; }
                Ob[m1 * OSM1 + m2 * OSM2 + n1 * OSN1 + n2 * OSN2] = accv(acc, i, j);
            }
        }
    }
}

// Direct wrappers.
template<int M, int N, int K, int TM, int TN,
         int NM2, int OSM1, int OSM2, int NN2, int OSN1, int OSN2,
         int AOFF, int BOFF, int OOFF>
__device__ __forceinline__ void mmd(float* __restrict__ lds, int tid) {
    float2 acc[TM][TN / 2];
    mm_acc<M, N, K, TM, TN, AOFF, BOFF>(lds, tid, acc);
    mm_wr<M, N, TM, TN, NM2, OSM1, OSM2, NN2, OSN1, OSN2, OOFF>(lds, tid, acc);
}

template<int M, int N, int K, int TM, int TN,
         int NM2, int OSM1, int OSM2, int NN2, int OSN1, int OSN2,
         int AOFF, int PL, int OOFF>
__device__ __forceinline__ void mmdGB(float* __restrict__ lds, const float* __restrict__ W,
                                      float a0, float b0, float a1, float b1, int tid) {
    float2 acc[TM][TN / 2];
    mm_accGB<M, N, K, TM, TN, AOFF, PL>(lds, W, a0, b0, a1, b1, tid, acc);
    mm_wr<M, N, TM, TN, NM2, OSM1, OSM2, NN2, OSN1, OSN2, OOFF>(lds, tid, acc);
}

template<int M, int N, int K, int TM, int TN,
         int NM2, int OSM1, int OSM2, int NN2, int OSN1, int OSN2,
         int BOFF, int PL, int OOFF>
__device__ __forceinline__ void mmdGA(float* __restrict__ lds, const float* __restrict__ W,
                                      float a0, float b0, float a1, float b1, int tid) {
    float2 acc[TM][TN / 2];
    mm_accGA<M, N, K, TM, TN, BOFF, PL>(lds, W, a0, b0, a1, b1, tid, acc);
    mm_wr<M, N, TM, TN, NM2, OSM1, OSM2, NN2, OSN1, OSN2, OOFF>(lds, tid, acc);
}

// ---------------------------------------------------------------------------
// Main: single fused kernel. Gram partials recomputed per block (weights
// L2-hot) into the arena's first 192 floats (aliased; arena written later),
// then structure identical to R11 (verified, 60.0 us).
// ---------------------------------------------------------------------------
__global__ __launch_bounds__(NTHREADS, 4) void peps_main(const float* __restrict__ x, PW pw,
                                                         float* __restrict__ out) {
    __shared__ float lds[2 * ARENA];
    __shared__ float cfa[2][16], cfb[2][16];
    __shared__ float red[4][10];

    const int tid = threadIdx.x;
    const int s0 = blockIdx.x * 2;
    const int lane = tid & 63, wv = tid >> 6;

    // ---- fused gram prologue (gpart aliases lds[0..191]) ----
    if (tid < 192) lds[tid] = 0.f;
    __syncthreads();
    {
        // node 10 (m=12960) split across 4 waves; rest statically balanced.
        // Coverage audit: 10(x4) | 5,0 | 6,3 | 9,12,14 | 1,2,4,7,8,11,13,15  = all 16.
        gram_node(pw, 10, wv * 3240, 3240, lane, wv, lds);
        if (wv == 0) {
            gram_node(pw, 5, 0, 1296, lane, wv, lds);
            gram_node(pw, 0, 0, 36, lane, wv, lds);
        } else if (wv == 1) {
            gram_node(pw, 6, 0, 1296, lane, wv, lds);
            gram_node(pw, 3, 0, 36, lane, wv, lds);
        } else if (wv == 2) {
            gram_node(pw, 9, 0, 1296, lane, wv, lds);
            gram_node(pw, 12, 0, 36, lane, wv, lds);
            gram_node(pw, 14, 0, 216, lane, wv, lds);
        } else {
            gram_node(pw, 1, 0, 216, lane, wv, lds);
            gram_node(pw, 2, 0, 216, lane, wv, lds);
            gram_node(pw, 4, 0, 216, lane, wv, lds);
            gram_node(pw, 7, 0, 216, lane, wv, lds);
            gram_node(pw, 8, 0, 216, lane, wv, lds);
            gram_node(pw, 11, 0, 216, lane, wv, lds);
            gram_node(pw, 13, 0, 216, lane, wv, lds);
            gram_node(pw, 15, 0, 36, lane, wv, lds);
        }
    }
    __syncthreads();

    if (tid < 32) {
        const int sl = tid >> 4, n = tid & 15;
        const float a = x[(s0 + sl) * 32 + n * 2 + 0];
        const float b = x[(s0 + sl) * 32 + n * 2 + 1];
        float g0 = 0.f, g1 = 0.f, g2 = 0.f;
#pragma unroll
        for (int q = 0; q < 4; q++) {
            g0 += lds[(n * 4 + q) * 3 + 0];
            g1 += lds[(n * 4 + q) * 3 + 1];
            g2 += lds[(n * 4 + q) * 3 + 2];
        }
        const float inv = 1.f / sqrtf(a * a * g0 + 2.f * a * b * g1 + b * b * g2);
        cfa[sl][n] = a * inv; cfb[sl][n] = b * inv;
    }
    __syncthreads();

#define CF(WI) cfa[0][WI], cfb[0][WI], cfa[1][WI], cfb[1][WI]

    // P0: stage permuted weights: t12->C, t00->W0, t02->W2, t20->W20, t31->W31, t32->W3
    stg_pm<6, 6, 6, 6, 216, 1, 36, 6, SC>(lds, pw.w[6], CF(6), tid);
    stg_pm<1, 1, 6, 6, 0, 0, 1, 6, W0A>(lds, pw.w[0], CF(0), tid);
    stg_pm<1, 6, 6, 6, 0, 1, 36, 6, W2A>(lds, pw.w[2], CF(2), tid);
    stg_pm<1, 6, 6, 6, 0, 6, 36, 1, W20A>(lds, pw.w[8], CF(8), tid);
    stg_pm<1, 6, 6, 6, 0, 6, 36, 1, W31A>(lds, pw.w[13], CF(13), tid);
    stg_pm<1, 6, 6, 6, 0, 1, 36, 6, W3A>(lds, pw.w[14], CF(14), tid);
    __syncthreads();

    // Ph1: S1 TL1 = t00(W0) x t01(G w1) -> P
    mmdGB<6, 36, 6, 2, 4, 6, 0, 36, 36, 0, 1, W0A, 216, SP>(lds, pw.w[1], CF(1), tid);
    __syncthreads();

    // Ph2: S2 TL2 = TL1(P) x t10(G w4) -> A
    mmdGB<36, 36, 6, 4, 4, 6, 216, 6, 6, 1, 36, SP, 216, SA>(lds, pw.w[4], CF(4), tid);
    __syncthreads();

    // Ph3: S3 TL = TL2(A) x t11(G w5) -> B ; S4 TR1 = t02(W2) x t03(G w3) -> P
    mmdGB<36, 36, 36, 4, 4, 6, 216, 6, 6, 1, 36, SA, 1296, SB>(lds, pw.w[5], CF(5), tid);
    mmdGB<36, 6, 6, 4, 2, 36, 0, 1, 6, 0, 36, W2A, 36, SP>(lds, pw.w[3], CF(3), tid);
    __syncthreads();

    // Ph4: S5 TR2 = TR1(P) x t13(G w7) -> A (TL2 dead)
    mmdGB<36, 36, 6, 4, 4, 6, 6, 216, 6, 36, 1, SP, 216, SA>(lds, pw.w[7], CF(7), tid);
    __syncthreads();

    // Ph5: S6 TR' = t12(C) x TR2(A) [K=36] (defer -> A)
    {
        float2 a6[4][2];
        mm_acc<36, 36, 36, 4, 4, SC, SA>(lds, tid, a6);
        __syncthreads();
        mm_wr<36, 36, 4, 4, 6, 36, 6, 6, 216, 1, SA>(lds, tid, a6);  // TR' [h01][h11][v12][v13]
    }
    __syncthreads();

    // Ph6: S7 TOP = TL(B) x TR'(A) [K=36] (defer -> B)
    //      stage t21 -> C (t12 dead) ; S8 BL1 = t30(G w12) x t20(W20) -> P
    {
        float2 a7[4][2];
        mm_acc<36, 36, 36, 4, 4, SB, SA>(lds, tid, a7);
        stg_pm<6, 6, 6, 6, 36, 6, 216, 1, SC>(lds, pw.w[9], CF(9), tid);
        mmdGA<6, 36, 6, 2, 4, 6, 0, 36, 36, 0, 1, W20A, 36, SP>(lds, pw.w[12], CF(12), tid);
        __syncthreads();
        mm_wr<36, 36, 4, 4, 6, 216, 36, 6, 6, 1, SB>(lds, tid, a7); // TOP [v10][v11][v12][v13]
    }
    __syncthreads();

    // Ph7: S9 BL2 = BL1(P) x t31(W31) -> A (TR' dead)
    //      stage t23 -> W2 (t02 dead since Ph3): staged [v23][v13,h22]
    mmd<36, 36, 6, 4, 4, 6, 6, 216, 6, 36, 1, SP, W31A, SA>(lds, tid);
    stg_pm<1, 6, 6, 6, 0, 1, 36, 6, W2A>(lds, pw.w[11], CF(11), tid);
    __syncthreads();

    // Ph8: S10 BL = BL2(A) x t21(C) [K=36] (defer -> A)
    {
        float2 a10[4][2];
        mm_acc<36, 36, 36, 4, 4, SA, SC>(lds, tid, a10);
        __syncthreads();
        mm_wr<36, 36, 4, 4, 6, 216, 6, 6, 36, 1, SA>(lds, tid, a10); // BL [v10][v11][h31][h21]
    }
    __syncthreads();

    // Ph9: S11 M1 = TOP(B) x BL(A) -> C (t21 dead, direct)
    //      S12 R1 = t23(W2, staged perm) x t33(G w15, identity) -> P
    mmd<36, 36, 36, 4, 4, 6, 6, 216, 6, 36, 1, SB, SA, SC>(lds, tid);
    mmdGB<36, 6, 6, 4, 2, 36, 0, 1, 6, 0, 36, W2A, 36, SP>(lds, pw.w[15], CF(15), tid);
    __syncthreads();

    // Ph10: S13 R' = R1(P) x t32(W3) -> B (TOP dead, direct)
    mmd<36, 36, 6, 4, 4, 6, 216, 1, 6, 6, 36, SP, W3A, SB>(lds, tid);
    __syncthreads();

    // Ph11: S14 E = M1(C) x R'(B) -> A (BL dead, direct); E [v12][h21][v22][h22]
    mmd<36, 36, 36, 4, 4, 6, 216, 36, 6, 6, 1, SC, SB, SA>(lds, tid);
    __syncthreads();

    // ---- epilogue: per-sample half-block (threads 0-127 -> sample0, 128-255
    // -> sample1) halves live register state -> no scratch spill (R11). ----
    {
        const int half = tid >> 7;          // sample index
        const int t = tid & 127;
        const float aC = cfa[half][10], bC = cfb[half][10];
        const float* __restrict__ w0 = pw.w[10];
        const float* __restrict__ w1 = w0 + 12960;
        float p[10];
#pragma unroll
        for (int o = 0; o < 10; o++) p[o] = 0.f;
        for (int f = t; f < 324; f += 128) {
            const float4 E = *reinterpret_cast<const float4*>(lds + half * ARENA + SA + 4 * f);
            const float ev[4] = {E.x, E.y, E.z, E.w};
#pragma unroll
            for (int u = 0; u < 4; u++) {
                const int e = 4 * f + u;
                const float* __restrict__ q0 = w0 + e * 10;
                const float* __restrict__ q1 = w1 + e * 10;
#pragma unroll
                for (int o = 0; o < 10; o++)
                    p[o] += ev[u] * (aC * q0[o] + bC * q1[o]);
            }
        }
#pragma unroll
        for (int o = 0; o < 10; o++)
            for (int off = 32; off > 0; off >>= 1)
                p[o] += __shfl_down(p[o], off, 64);
        if (lane == 0) {
#pragma unroll
            for (int o = 0; o < 10; o++) red[wv][o] = p[o];
        }
        __syncthreads();
        if (tid < 2) {
            float r[10];
            float ss = 0.f;
#pragma unroll
            for (int o = 0; o < 10; o++) {
                r[o] = red[2 * tid][o] + red[2 * tid + 1][o];
                ss += r[o] * r[o];
            }
            const float inv = 1.f / sqrtf(ss);
#pragma unroll
            for (int o = 0; o < 10; o++) out[(s0 + tid) * 10 + o] = r[o] * inv;
        }
    }
#undef CF
}

extern "C" void kernel_launch(void* const* d_in, const int* in_sizes, int n_in,
                              void* d_out, int out_size, void* d_ws, size_t ws_size,
                              hipStream_t stream) {
    PW pw;
    for (int k = 0; k < 16; k++) {
        pw.w[k] = (const float*)d_in[1 + k];
        pw.perp[k] = in_sizes[1 + k] / 2;
    }
    const float* x = (const float*)d_in[0];
    const int B = out_size / 10;            // 2048 samples
    peps_main<<<B / 2, NTHREADS, 0, stream>>>(x, pw, (float*)d_out);
}

// Round 14
// 138.452 us; speedup vs baseline: 1.0433x; 1.0433x over previous
//
#include <hip/hip_runtime.h>
#include <math.h>

#define NTHREADS 256

// 16 node weight pointers.
struct PW {
    const float* w[16];
    int perp[16];
};

// ---------------------------------------------------------------------------
// Gram precompute, 4 partial slices per node (64 blocks), float4 loads.
// ---------------------------------------------------------------------------
__global__ __launch_bounds__(NTHREADS) void gram64(PW pw, float* __restrict__ g) {
    const int n = blockIdx.x >> 2, sl = blockIdx.x & 3;
    const float* __restrict__ W = pw.w[n];
    const int m = pw.perp[n];
    float s00 = 0.f, s01 = 0.f, s11 = 0.f;
    for (int e = (sl * NTHREADS + threadIdx.x) * 4; e < m; e += NTHREADS * 16) {
        const float4 a = *reinterpret_cast<const float4*>(W + e);
        const float4 b = *reinterpret_cast<const float4*>(W + m + e);
        s00 += a.x * a.x + a.y * a.y + a.z * a.z + a.w * a.w;
        s01 += a.x * b.x + a.y * b.y + a.z * b.z + a.w * b.w;
        s11 += b.x * b.x + b.y * b.y + b.z * b.z + b.w * b.w;
    }
    for (int off = 32; off > 0; off >>= 1) {
        s00 += __shfl_down(s00, off, 64);
        s01 += __shfl_down(s01, off, 64);
        s11 += __shfl_down(s11, off, 64);
    }
    __shared__ float red[4][3];
    const int lane = threadIdx.x & 63, wv = threadIdx.x >> 6;
    if (lane == 0) { red[wv][0] = s00; red[wv][1] = s01; red[wv][2] = s11; }
    __syncthreads();
    if (threadIdx.x == 0) {
        float t0 = 0.f, t1 = 0.f, t2 = 0.f;
        for (int i = 0; i < 4; i++) { t0 += red[i][0]; t1 += red[i][1]; t2 += red[i][2]; }
        g[n * 12 + sl * 3 + 0] = t0; g[n * 12 + sl * 3 + 1] = t1; g[n * 12 + sl * 3 + 2] = t2;
    }
}

// ---------------------------------------------------------------------------
// LDS arena per sample (floats). Structure identical to R9/R11 (verified).
// ---------------------------------------------------------------------------
constexpr int SA = 0, SB = 1296, SC = 2592, SP = 3888;
constexpr int W0A = 4104, W2A = 4140, W20A = 4356, W31A = 4572, W3A = 4788;
constexpr int ARENA = 5004;   // 2*5004*4 = 40032 B -> 4 blocks/CU

// Staging with permutation.
template<int D0, int D1, int D2, int D3, int S0, int S1, int S2, int S3, int DST>
__device__ __forceinline__ void stg_pm(float* __restrict__ lds, const float* __restrict__ W,
                                       float a0, float b0, float a1, float b1, int tid) {
    constexpr int TOT = D0 * D1 * D2 * D3;
    for (int e = tid; e < 2 * TOT; e += NTHREADS) {
        const int s = (e >= TOT);
        const int d = e - s * TOT;
        int r = d;
        const int i3 = r % D3; r /= D3;
        const int i2 = r % D2; r /= D2;
        const int i1 = r % D1;
        const int i0 = r / D1;
        const int src = i0 * S0 + i1 * S1 + i2 * S2 + i3 * S3;
        const float al = s ? a1 : a0, be = s ? b1 : b0;
        lds[s * ARENA + DST + d] = al * W[src] + be * W[TOT + src];
    }
}

// ---------------------------------------------------------------------------
// mm cores with PACKED accumulators (R11-verified).
// ---------------------------------------------------------------------------
#define PK_FMA(ACC, AV, BV) { (ACC).x += (AV) * (BV).x; (ACC).y += (AV) * (BV).y; }

template<int M, int N, int K, int TM, int TN, int AOFF, int BOFF>
__device__ __forceinline__ void mm_acc(const float* __restrict__ lds, int tid,
                                       float2 (&acc)[TM][TN / 2]) {
    constexpr int WM = M / TM, WN = N / TN, PER_S = WM * WN, TOT = 2 * PER_S;
    static_assert(TOT <= NTHREADS, "tile overflow");
    if (tid >= TOT) return;
    const int s = (tid >= PER_S);
    const int r = tid - s * PER_S;
    const int mt = r / WN, nt = r - mt * WN;
    const float* __restrict__ Ab = lds + s * ARENA + AOFF + mt * TM;
    const float* __restrict__ Bb = lds + s * ARENA + BOFF + nt * TN;
#pragma unroll
    for (int i = 0; i < TM; i++)
#pragma unroll
        for (int j = 0; j < TN / 2; j++) { acc[i][j].x = 0.f; acc[i][j].y = 0.f; }
#pragma unroll 6
    for (int k = 0; k < K; ++k) {
        float a[TM]; float2 b[TN / 2];
        if constexpr (TM == 4) {
            const float4 v = *reinterpret_cast<const float4*>(Ab + k * M);
            a[0] = v.x; a[1] = v.y; a[2] = v.z; a[3] = v.w;
        } else {
            const float2 v = *reinterpret_cast<const float2*>(Ab + k * M);
            a[0] = v.x; a[1] = v.y;
        }
        if constexpr (TN == 4) {
            const float4 v = *reinterpret_cast<const float4*>(Bb + k * N);
            b[0].x = v.x; b[0].y = v.y; b[1].x = v.z; b[1].y = v.w;
        } else {
            b[0] = *reinterpret_cast<const float2*>(Bb + k * N);
        }
#pragma unroll
        for (int i = 0; i < TM; i++)
#pragma unroll
            for (int j = 0; j < TN / 2; j++) PK_FMA(acc[i][j], a[i], b[j]);
    }
}

// A from LDS, B from GLOBAL identity weight (planes W, W+PL), packed combine.
template<int M, int N, int K, int TM, int TN, int AOFF, int PL>
__device__ __forceinline__ void mm_accGB(const float* __restrict__ lds,
                                         const float* __restrict__ W,
                                         float a0, float b0, float a1, float b1,
                                         int tid, float2 (&acc)[TM][TN / 2]) {
    constexpr int WM = M / TM, WN = N / TN, PER_S = WM * WN, TOT = 2 * PER_S;
    static_assert(TOT <= NTHREADS, "tile overflow");
    if (tid >= TOT) return;
    const int s = (tid >= PER_S);
    const int r = tid - s * PER_S;
    const int mt = r / WN, nt = r - mt * WN;
    const float al = s ? a1 : a0, be = s ? b1 : b0;
    const float* __restrict__ Ab = lds + s * ARENA + AOFF + mt * TM;
    const float* __restrict__ Bb = W + nt * TN;
#pragma unroll
    for (int i = 0; i < TM; i++)
#pragma unroll
        for (int j = 0; j < TN / 2; j++) { acc[i][j].x = 0.f; acc[i][j].y = 0.f; }
#pragma unroll 6
    for (int k = 0; k < K; ++k) {
        float a[TM]; float2 b[TN / 2];
        if constexpr (TM == 4) {
            const float4 v = *reinterpret_cast<const float4*>(Ab + k * M);
            a[0] = v.x; a[1] = v.y; a[2] = v.z; a[3] = v.w;
        } else {
            const float2 v = *reinterpret_cast<const float2*>(Ab + k * M);
            a[0] = v.x; a[1] = v.y;
        }
        if constexpr (TN == 4) {
            const float4 u0 = *reinterpret_cast<const float4*>(Bb + k * N);
            const float4 u1 = *reinterpret_cast<const float4*>(Bb + PL + k * N);
            b[0].x = al * u0.x + be * u1.x; b[0].y = al * u0.y + be * u1.y;
            b[1].x = al * u0.z + be * u1.z; b[1].y = al * u0.w + be * u1.w;
        } else {
            const float2 u0 = *reinterpret_cast<const float2*>(Bb + k * N);
            const float2 u1 = *reinterpret_cast<const float2*>(Bb + PL + k * N);
            b[0].x = al * u0.x + be * u1.x; b[0].y = al * u0.y + be * u1.y;
        }
#pragma unroll
        for (int i = 0; i < TM; i++)
#pragma unroll
            for (int j = 0; j < TN / 2; j++) PK_FMA(acc[i][j], a[i], b[j]);
    }
}

// A from GLOBAL identity weight, B from LDS.
template<int M, int N, int K, int TM, int TN, int BOFF, int PL>
__device__ __forceinline__ void mm_accGA(const float* __restrict__ lds,
                                         const float* __restrict__ W,
                                         float a0, float b0, float a1, float b1,
                                         int tid, float2 (&acc)[TM][TN / 2]) {
    constexpr int WM = M / TM, WN = N / TN, PER_S = WM * WN, TOT = 2 * PER_S;
    static_assert(TOT <= NTHREADS, "tile overflow");
    if (tid >= TOT) return;
    const int s = (tid >= PER_S);
    const int r = tid - s * PER_S;
    const int mt = r / WN, nt = r - mt * WN;
    const float al = s ? a1 : a0, be = s ? b1 : b0;
    const float* __restrict__ Ab = W + mt * TM;
    const float* __restrict__ Bb = lds + s * ARENA + BOFF + nt * TN;
#pragma unroll
    for (int i = 0; i < TM; i++)
#pragma unroll
        for (int j = 0; j < TN / 2; j++) { acc[i][j].x = 0.f; acc[i][j].y = 0.f; }
#pragma unroll 6
    for (int k = 0; k < K; ++k) {
        float a[TM]; float2 b[TN / 2];
        if constexpr (TM == 4) {
            const float4 u0 = *reinterpret_cast<const float4*>(Ab + k * M);
            const float4 u1 = *reinterpret_cast<const float4*>(Ab + PL + k * M);
            a[0] = al * u0.x + be * u1.x; a[1] = al * u0.y + be * u1.y;
            a[2] = al * u0.z + be * u1.z; a[3] = al * u0.w + be * u1.w;
        } else {
            const float2 u0 = *reinterpret_cast<const float2*>(Ab + k * M);
            const float2 u1 = *reinterpret_cast<const float2*>(Ab + PL + k * M);
            a[0] = al * u0.x + be * u1.x; a[1] = al * u0.y + be * u1.y;
        }
        if constexpr (TN == 4) {
            const float4 v = *reinterpret_cast<const float4*>(Bb + k * N);
            b[0].x = v.x; b[0].y = v.y; b[1].x = v.z; b[1].y = v.w;
        } else {
            b[0] = *reinterpret_cast<const float2*>(Bb + k * N);
        }
#pragma unroll
        for (int i = 0; i < TM; i++)
#pragma unroll
            for (int j = 0; j < TN / 2; j++) PK_FMA(acc[i][j], a[i], b[j]);
    }
}

// Scalar accessor into packed acc (compile-time j in unrolled loops).
template<int TM, int TNH>
__device__ __forceinline__ float accv(const float2 (&acc)[TM][TNH], int i, int j) {
    return (j & 1) ? acc[i][j >> 1].y : acc[i][j >> 1].x;
}

// Write with per-axis strides (stride lists verified R2/R7/R9/R11).
template<int M, int N, int TM, int TN,
         int NM2, int OSM1, int OSM2, int NN2, int OSN1, int OSN2, int OOFF>
__device__ __forceinline__ void mm_wr(float* __restrict__ lds, int tid,
                                      const float2 (&acc)[TM][TN / 2]) {
    constexpr int WM = M / TM, WN = N / TN, PER_S = WM * WN, TOT = 2 * PER_S;
    if (tid >= TOT) return;
    const int s = (tid >= PER_S);
    const int r = tid - s * PER_S;
    const int mt = r / WN, nt = r - mt * WN;
    float* __restrict__ Ob = lds + s * ARENA + OOFF;
    constexpr bool NCONT = (TN == 4) && (OSN2 == 1) && ((NN2 >= N) || (OSN1 == NN2));
    constexpr bool MCONT = (TM == 4) && (OSM2 == 1) && ((NM2 >= M) || (OSM1 == NM2));
    if constexpr (NCONT) {
        const int nb = nt * TN;
#pragma unroll
        for (int i = 0; i < TM; i++) {
            const int m = mt * TM + i;
            int m1, m2;
            if constexpr (NM2 >= M) { m1 = 0; m2 = m; }
            else                    { m1 = m / NM2; m2 = m - m1 * NM2; }
            float4 v; v.x = acc[i][0].x; v.y = acc[i][0].y; v.z = acc[i][1].x; v.w = acc[i][1].y;
            *reinterpret_cast<float4*>(Ob + m1 * OSM1 + m2 * OSM2 + nb) = v;
        }
    } else if constexpr (MCONT) {
        const int mb = mt * TM;
#pragma unroll
        for (int j = 0; j < TN; j++) {
            const int n = nt * TN + j;
            int n1, n2;
            if constexpr (NN2 >= N) { n1 = 0; n2 = n; }
            else                    { n1 = n / NN2; n2 = n - n1 * NN2; }
            float4 v;
            v.x = accv(acc, 0, j); v.y = accv(acc, 1, j);
            v.z = accv(acc, 2, j); v.w = accv(acc, 3, j);
            *reinterpret_cast<float4*>(Ob + n1 * OSN1 + n2 * OSN2 + mb) = v;
        }
    } else {
#pragma unroll
        for (int i = 0; i < TM; i++) {
            const int m = mt * TM + i;
            int m1, m2;
            if constexpr (NM2 >= M) { m1 = 0; m2 = m; }
            else                    { m1 = m / NM2; m2 = m - m1 * NM2; }
#pragma unroll
            for (int j = 0; j < TN; j++) {
                const int n = nt * TN + j;
                int n1, n2;
                if constexpr (NN2 >= N) { n1 = 0; n2 = n; }
                else                    { n1 = n / NN2; n2 = n - n1 * NN2; }
                Ob[m1 * OSM1 + m2 * OSM2 + n1 * OSN1 + n2 * OSN2] = accv(acc, i, j);
            }
        }
    }
}

// Direct wrappers.
template<int M, int N, int K, int TM, int TN,
         int NM2, int OSM1, int OSM2, int NN2, int OSN1, int OSN2,
         int AOFF, int BOFF, int OOFF>
__device__ __forceinline__ void mmd(float* __restrict__ lds, int tid) {
    float2 acc[TM][TN / 2];
    mm_acc<M, N, K, TM, TN, AOFF, BOFF>(lds, tid, acc);
    mm_wr<M, N, TM, TN, NM2, OSM1, OSM2, NN2, OSN1, OSN2, OOFF>(lds, tid, acc);
}

template<int M, int N, int K, int TM, int TN,
         int NM2, int OSM1, int OSM2, int NN2, int OSN1, int OSN2,
         int AOFF, int PL, int OOFF>
__device__ __forceinline__ void mmdGB(float* __restrict__ lds, const float* __restrict__ W,
                                      float a0, float b0, float a1, float b1, int tid) {
    float2 acc[TM][TN / 2];
    mm_accGB<M, N, K, TM, TN, AOFF, PL>(lds, W, a0, b0, a1, b1, tid, acc);
    mm_wr<M, N, TM, TN, NM2, OSM1, OSM2, NN2, OSN1, OSN2, OOFF>(lds, tid, acc);
}

template<int M, int N, int K, int TM, int TN,
         int NM2, int OSM1, int OSM2, int NN2, int OSN1, int OSN2,
         int BOFF, int PL, int OOFF>
__device__ __forceinline__ void mmdGA(float* __restrict__ lds, const float* __restrict__ W,
                                      float a0, float b0, float a1, float b1, int tid) {
    float2 acc[TM][TN / 2];
    mm_accGA<M, N, K, TM, TN, BOFF, PL>(lds, W, a0, b0, a1, b1, tid, acc);
    mm_wr<M, N, TM, TN, NM2, OSM1, OSM2, NN2, OSN1, OSN2, OOFF>(lds, tid, acc);
}

// ---------------------------------------------------------------------------
// Main: one block = 2 samples, 4 blocks/CU. R11-verified structure (60.0 us):
// identity-layout weights read from global (L2-hot) with on-the-fly combine;
// permuted weights staged in LDS; packed math; de-spilled split epilogue.
// ---------------------------------------------------------------------------
__global__ __launch_bounds__(NTHREADS, 4) void peps_main(const float* __restrict__ x, PW pw,
                                                         const float* __restrict__ gram,
                                                         float* __restrict__ out) {
    __shared__ float lds[2 * ARENA];
    __shared__ float cfa[2][16], cfb[2][16];
    __shared__ float red[4][10];

    const int tid = threadIdx.x;
    const int s0 = blockIdx.x * 2;

    if (tid < 32) {
        const int sl = tid >> 4, n = tid & 15;
        const float a = x[(s0 + sl) * 32 + n * 2 + 0];
        const float b = x[(s0 + sl) * 32 + n * 2 + 1];
        float g0 = 0.f, g1 = 0.f, g2 = 0.f;
#pragma unroll
        for (int q = 0; q < 4; q++) {
            g0 += gram[n * 12 + q * 3 + 0];
            g1 += gram[n * 12 + q * 3 + 1];
            g2 += gram[n * 12 + q * 3 + 2];
        }
        const float inv = 1.f / sqrtf(a * a * g0 + 2.f * a * b * g1 + b * b * g2);
        cfa[sl][n] = a * inv; cfb[sl][n] = b * inv;
    }
    __syncthreads();

#define CF(WI) cfa[0][WI], cfb[0][WI], cfa[1][WI], cfb[1][WI]

    // P0: stage permuted weights: t12->C, t00->W0, t02->W2, t20->W20, t31->W31, t32->W3
    stg_pm<6, 6, 6, 6, 216, 1, 36, 6, SC>(lds, pw.w[6], CF(6), tid);
    stg_pm<1, 1, 6, 6, 0, 0, 1, 6, W0A>(lds, pw.w[0], CF(0), tid);
    stg_pm<1, 6, 6, 6, 0, 1, 36, 6, W2A>(lds, pw.w[2], CF(2), tid);
    stg_pm<1, 6, 6, 6, 0, 6, 36, 1, W20A>(lds, pw.w[8], CF(8), tid);
    stg_pm<1, 6, 6, 6, 0, 6, 36, 1, W31A>(lds, pw.w[13], CF(13), tid);
    stg_pm<1, 6, 6, 6, 0, 1, 36, 6, W3A>(lds, pw.w[14], CF(14), tid);
    __syncthreads();

    // Ph1: S1 TL1 = t00(W0) x t01(G w1) -> P
    mmdGB<6, 36, 6, 2, 4, 6, 0, 36, 36, 0, 1, W0A, 216, SP>(lds, pw.w[1], CF(1), tid);
    __syncthreads();

    // Ph2: S2 TL2 = TL1(P) x t10(G w4) -> A
    mmdGB<36, 36, 6, 4, 4, 6, 216, 6, 6, 1, 36, SP, 216, SA>(lds, pw.w[4], CF(4), tid);
    __syncthreads();

    // Ph3: S3 TL = TL2(A) x t11(G w5) -> B ; S4 TR1 = t02(W2) x t03(G w3) -> P
    mmdGB<36, 36, 36, 4, 4, 6, 216, 6, 6, 1, 36, SA, 1296, SB>(lds, pw.w[5], CF(5), tid);
    mmdGB<36, 6, 6, 4, 2, 36, 0, 1, 6, 0, 36, W2A, 36, SP>(lds, pw.w[3], CF(3), tid);
    __syncthreads();

    // Ph4: S5 TR2 = TR1(P) x t13(G w7) -> A (TL2 dead)
    mmdGB<36, 36, 6, 4, 4, 6, 6, 216, 6, 36, 1, SP, 216, SA>(lds, pw.w[7], CF(7), tid);
    __syncthreads();

    // Ph5: S6 TR' = t12(C) x TR2(A) [K=36] (defer -> A)
    {
        float2 a6[4][2];
        mm_acc<36, 36, 36, 4, 4, SC, SA>(lds, tid, a6);
        __syncthreads();
        mm_wr<36, 36, 4, 4, 6, 36, 6, 6, 216, 1, SA>(lds, tid, a6);  // TR' [h01][h11][v12][v13]
    }
    __syncthreads();

    // Ph6: S7 TOP = TL(B) x TR'(A) [K=36] (defer -> B)
    //      stage t21 -> C (t12 dead) ; S8 BL1 = t30(G w12) x t20(W20) -> P
    {
        float2 a7[4][2];
        mm_acc<36, 36, 36, 4, 4, SB, SA>(lds, tid, a7);
        stg_pm<6, 6, 6, 6, 36, 6, 216, 1, SC>(lds, pw.w[9], CF(9), tid);
        mmdGA<6, 36, 6, 2, 4, 6, 0, 36, 36, 0, 1, W20A, 36, SP>(lds, pw.w[12], CF(12), tid);
        __syncthreads();
        mm_wr<36, 36, 4, 4, 6, 216, 36, 6, 6, 1, SB>(lds, tid, a7); // TOP [v10][v11][v12][v13]
    }
    __syncthreads();

    // Ph7: S9 BL2 = BL1(P) x t31(W31) -> A (TR' dead)
    //      stage t23 -> W2 (t02 dead since Ph3): staged [v23][v13,h22]
    mmd<36, 36, 6, 4, 4, 6, 6, 216, 6, 36, 1, SP, W31A, SA>(lds, tid);
    stg_pm<1, 6, 6, 6, 0, 1, 36, 6, W2A>(lds, pw.w[11], CF(11), tid);
    __syncthreads();

    // Ph8: S10 BL = BL2(A) x t21(C) [K=36] (defer -> A)
    {
        float2 a10[4][2];
        mm_acc<36, 36, 36, 4, 4, SA, SC>(lds, tid, a10);
        __syncthreads();
        mm_wr<36, 36, 4, 4, 6, 216, 6, 6, 36, 1, SA>(lds, tid, a10); // BL [v10][v11][h31][h21]
    }
    __syncthreads();

    // Ph9: S11 M1 = TOP(B) x BL(A) -> C (t21 dead, direct)
    //      S12 R1 = t23(W2, staged perm) x t33(G w15, identity) -> P
    mmd<36, 36, 36, 4, 4, 6, 6, 216, 6, 36, 1, SB, SA, SC>(lds, tid);
    mmdGB<36, 6, 6, 4, 2, 36, 0, 1, 6, 0, 36, W2A, 36, SP>(lds, pw.w[15], CF(15), tid);
    __syncthreads();

    // Ph10: S13 R' = R1(P) x t32(W3) -> B (TOP dead, direct)
    mmd<36, 36, 6, 4, 4, 6, 216, 1, 6, 6, 36, SP, W3A, SB>(lds, tid);
    __syncthreads();

    // Ph11: S14 E = M1(C) x R'(B) -> A (BL dead, direct); E [v12][h21][v22][h22]
    mmd<36, 36, 36, 4, 4, 6, 216, 36, 6, 6, 1, SC, SB, SA>(lds, tid);
    __syncthreads();

    // ---- epilogue: per-sample half-block (threads 0-127 -> sample0, 128-255
    // -> sample1) halves live register state -> no scratch spill (R11). ----
    {
        const int half = tid >> 7;          // sample index
        const int t = tid & 127;
        const float aC = cfa[half][10], bC = cfb[half][10];
        const float* __restrict__ w0 = pw.w[10];
        const float* __restrict__ w1 = w0 + 12960;
        float p[10];
#pragma unroll
        for (int o = 0; o < 10; o++) p[o] = 0.f;
        for (int f = t; f < 324; f += 128) {
            const float4 E = *reinterpret_cast<const float4*>(lds + half * ARENA + SA + 4 * f);
            const float ev[4] = {E.x, E.y, E.z, E.w};
#pragma unroll
            for (int u = 0; u < 4; u++) {
                const int e = 4 * f + u;
                const float* __restrict__ q0 = w0 + e * 10;
                const float* __restrict__ q1 = w1 + e * 10;
#pragma unroll
                for (int o = 0; o < 10; o++)
                    p[o] += ev[u] * (aC * q0[o] + bC * q1[o]);
            }
        }
#pragma unroll
        for (int o = 0; o < 10; o++)
            for (int off = 32; off > 0; off >>= 1)
                p[o] += __shfl_down(p[o], off, 64);
        const int lane = tid & 63, wv = tid >> 6;   // waves 0,1: sample0; 2,3: sample1
        if (lane == 0) {
#pragma unroll
            for (int o = 0; o < 10; o++) red[wv][o] = p[o];
        }
        __syncthreads();
        if (tid < 2) {
            float r[10];
            float ss = 0.f;
#pragma unroll
            for (int o = 0; o < 10; o++) {
                r[o] = red[2 * tid][o] + red[2 * tid + 1][o];
                ss += r[o] * r[o];
            }
            const float inv = 1.f / sqrtf(ss);
#pragma unroll
            for (int o = 0; o < 10; o++) out[(s0 + tid) * 10 + o] = r[o] * inv;
        }
    }
#undef CF
}

extern "C" void kernel_launch(void* const* d_in, const int* in_sizes, int n_in,
                              void* d_out, int out_size, void* d_ws, size_t ws_size,
                              hipStream_t stream) {
    PW pw;
    for (int k = 0; k < 16; k++) {
        pw.w[k] = (const float*)d_in[1 + k];
        pw.perp[k] = in_sizes[1 + k] / 2;
    }
    float* gram = (float*)d_ws;             // 16*12 floats (4 partial slices/node)
    gram64<<<64, NTHREADS, 0, stream>>>(pw, gram);

    const float* x = (const float*)d_in[0];
    const int B = out_size / 10;            // 2048 samples
    peps_main<<<B / 2, NTHREADS, 0, stream>>>(x, pw, gram, (float*)d_out);
}